// Round 7
// baseline (8955.165 us; speedup 1.0000x reference)
//
#include <hip/hip_runtime.h>
#include <stdint.h>

// Problem constants
#define SLEN 512
#define NBATCH 64
#define EMB 1024
#define HID 1024
#define G4 4096            // 4*H
#define D2H 2048           // 2*H
#define CT 64              // chunk timesteps
#define NC (SLEN/CT)       // 8 chunks
#define CROWS (CT*NBATCH)  // 4096 rows per chunk per dir
#define HSLOT (NBATCH*D2H) // elems per h timestep slot

typedef __bf16 bf16x8 __attribute__((ext_vector_type(8)));
typedef float  f32x4  __attribute__((ext_vector_type(4)));

__device__ __forceinline__ ushort f2bf(float x){
  union { float f; uint32_t u; } v; v.f = x;
  uint32_t r = (v.u + 0x7fffu + ((v.u >> 16) & 1u)) >> 16;   // RNE
  return (ushort)r;
}
__device__ __forceinline__ float bf2f(uint32_t u){
  union { uint32_t u; float f; } v; v.u = u << 16;
  return v.f;
}
__device__ __forceinline__ float sigm(float x){ return 1.f / (1.f + __expf(-x)); }
__device__ __forceinline__ float tanh_s(float x){ return 2.f / (1.f + __expf(-2.f*x)) - 1.f; }

__device__ __forceinline__ void async_ld16(const ushort* g, ushort* l){
  __builtin_amdgcn_global_load_lds(
      (const __attribute__((address_space(1))) uint32_t*)g,
      (__attribute__((address_space(3))) uint32_t*)l, 16, 0, 0);
}

// ---------------- zero a u32 region ----------------
__global__ void k_zero(uint32_t* p, int n){
  int i = blockIdx.x * 256 + threadIdx.x;
  if (i < n) p[i] = 0;
}

// ---------------- fp32 -> bf16 convert (vectorized x4) ----------------
__global__ void k_convert(const float4* __restrict__ src, ushort4* __restrict__ dst, int n4){
  int i = blockIdx.x * blockDim.x + threadIdx.x;
  if (i < n4){
    float4 v = src[i];
    ushort4 o; o.x = f2bf(v.x); o.y = f2bf(v.y); o.z = f2bf(v.z); o.w = f2bf(v.w);
    dst[i] = o;
  }
}

// ---------------- embedding gather for one chunk -> x_bf16 [CT][B][E] ----------
__global__ void k_gather_c(const int* __restrict__ inp, const float* __restrict__ emb,
                           ushort* __restrict__ xbf, int tbase){
  int row = blockIdx.x;            // i*64 + b
  int s = tbase + (row >> 6), b = row & 63;
  int t = threadIdx.x;
  int v = inp[b * SLEN + s];
  float4 x = ((const float4*)(emb + (size_t)v * EMB))[t];
  ushort4 o; o.x = f2bf(x.x); o.y = f2bf(x.y); o.z = f2bf(x.z); o.w = f2bf(x.w);
  ((ushort4*)(xbf + (size_t)row * EMB))[t] = o;
}

// ---------------- chunk GEMM (m97-style), unchanged ----------------
__global__ __launch_bounds__(256) void k_gemm(const ushort* __restrict__ A,
                                              const ushort* __restrict__ Bw,
                                              const float* __restrict__ bias,
                                              ushort* __restrict__ C, int K,
                                              size_t cDirStride){
  __shared__ __align__(16) ushort sA[128 * 32];
  __shared__ __align__(16) ushort sB[128 * 32];
  const int tid = threadIdx.x;
  const int d = blockIdx.z;
  const size_t mBase = (size_t)blockIdx.x * 128;
  const int nBase = blockIdx.y * 128;
  const ushort* Bd = Bw + (size_t)d * G4 * K;
  const float* biasd = bias + (size_t)d * G4;
  ushort* Cd = C + (size_t)d * cDirStride;
  const int w = tid >> 6, lane = tid & 63;
  const int quad = lane >> 4, c16 = lane & 15;
  const int m0 = (w >> 1) * 64, n0 = (w & 1) * 64;
  const int u0 = tid, u1 = tid + 256;
  const int r0 = u0 >> 2, k0 = (u0 & 3) * 8;
  const int r1 = u1 >> 2, k1 = (u1 & 3) * 8;

  f32x4 acc[4][4] = {};
  for (int kc = 0; kc < K; kc += 32){
    __syncthreads();
    async_ld16(A  + (mBase + r0) * (size_t)K + kc + k0, sA + u0 * 8);
    async_ld16(A  + (mBase + r1) * (size_t)K + kc + k1, sA + u1 * 8);
    async_ld16(Bd + (size_t)(nBase + r0) * K + kc + k0, sB + u0 * 8);
    async_ld16(Bd + (size_t)(nBase + r1) * K + kc + k1, sB + u1 * 8);
    __syncthreads();
    bf16x8 af[4], bfv[4];
#pragma unroll
    for (int mt = 0; mt < 4; ++mt)
      af[mt] = *(const bf16x8*)(sA + (m0 + mt * 16 + c16) * 32 + quad * 8);
#pragma unroll
    for (int nt = 0; nt < 4; ++nt)
      bfv[nt] = *(const bf16x8*)(sB + (n0 + nt * 16 + c16) * 32 + quad * 8);
#pragma unroll
    for (int mt = 0; mt < 4; ++mt)
#pragma unroll
      for (int nt = 0; nt < 4; ++nt)
        acc[mt][nt] = __builtin_amdgcn_mfma_f32_16x16x32_bf16(af[mt], bfv[nt], acc[mt][nt], 0, 0, 0);
  }
#pragma unroll
  for (int nt = 0; nt < 4; ++nt){
    int col = nBase + n0 + nt * 16 + c16;
    float bv = biasd[col];
#pragma unroll
    for (int mt = 0; mt < 4; ++mt){
      size_t rowb = mBase + m0 + mt * 16 + quad * 4;
#pragma unroll
      for (int r = 0; r < 4; ++r)
        Cd[(rowb + r) * G4 + col] = f2bf(acc[mt][nt][r] + bv);
    }
  }
}

// ---------------- combined persistent recurrent kernel: layer0(t) || layer1(t-1) ----
// Changes vs R5 (510us):
//  * XCD clustering: bid&7 = group(layer,d,mh), bid>>3 = jt. With bid%8 XCD
//    round-robin, each group's 64 blocks share one XCD -> h/flags/staging are
//    XCD-local L2 traffic.
//  * K-split waves: wave = (gate-pair gp, k-half kh). 16 iters x 2 ds_read_b128
//    x 4 MFMAs (A-frag shared by the wave's 2 gates) -> LDS K-loop reads HALVED.
//    Partials combined in sred: kh1 waves write, barrier, kh0 waves add, barrier.
//  * Per-thread flag-gated staging. FIX vs the R6 attempt: the source-side XOR
//    swizzle soff = stColU ^ ((row&7)<<3) flips producer-index bits 0..1
//    (producer = col>>4), so a thread's 16 staged rows touch EXACTLY the aligned
//    4-producer group (myJt&~3)+{0..3}. Poll all 4 flags (one 16B line,
//    agent-scope loads) before issuing the stage. R6 polled only myJt -> raced.
__global__ __launch_bounds__(256, 2) void k_rec(const ushort* __restrict__ xw0,
                                                const ushort* __restrict__ xw1,
                                                const ushort* __restrict__ whh0,
                                                const ushort* __restrict__ whh1,
                                                const ushort* __restrict__ hinit0,
                                                const ushort* __restrict__ hinit1,
                                                ushort* __restrict__ h0seq,
                                                ushort* __restrict__ h1seq,
                                                float* __restrict__ c0st,
                                                float* __restrict__ c1st,
                                                unsigned* __restrict__ flags,
                                                int act, int tbase0, int tbase1,
                                                unsigned tok0, unsigned tok1,
                                                const int* __restrict__ tgt_idx,
                                                float* __restrict__ tgt_out){
  const int bxp   = blockIdx.x;
  const int grp   = bxp & 7;             // (layer,d,mh) -> one XCD per group
  const int layer = grp >> 2;
  if (!((act >> layer) & 1)) return;     // ramp-in/out: half inactive
  const int d  = (grp >> 1) & 1;
  const int mh = grp & 1;
  const int jt = bxp >> 3;               // hidden tile (16 units), 0..63
  const int lb = jt * 4 + (d << 1) + mh; // per-layer unique block id 0..255

  const ushort* xw    = layer ? xw1    : xw0;
  const ushort* whh   = layer ? whh1   : whh0;
  const ushort* hinit = layer ? hinit1 : hinit0;
  ushort* hseq        = layer ? h1seq  : h0seq;
  float* cst          = layer ? c1st   : c0st;
  const int mode      = layer;                  // layer1 captures target rows
  const int tbase     = layer ? tbase1 : tbase0;
  const unsigned tok  = layer ? tok1 : tok0;

  const int tid = threadIdx.x;
  const int j0 = jt * 16;
  const int mb = mh * 32;
  const int w = tid >> 6, lane = tid & 63;
  const int quad = lane >> 4, c16 = lane & 15;
  const int gp = w & 1;                  // gate pair: gates {2gp, 2gp+1}
  const int kh = w >> 1;                 // k-half: t in [kh*16, kh*16+16)
  const int er = tid >> 3;               // epilogue: batch row 0..31
  const int ec = (tid & 7) * 2;          // epilogue: col pair 0,2,..,14

  // flag base for this block's group: [layer][d][mh][CT][64 producers]
  unsigned* fgrp = flags + (size_t)(((layer * 2 + d) * 2 + mh) * CT) * 64;

  __shared__ __align__(16) ushort hS[32 * 1024];  // 64 KB staged h(t-1) panel
  __shared__ float sred[4 * 32 * 17];             // [gate][row32][col16+pad]

  // ---- preload this wave's weights: 2 gates x 16 half-K frags = 128 regs ----
  bf16x8 bfr0[16], bfr1[16];
  {
    const ushort* wpA = whh + ((size_t)d * G4 + (size_t)(gp * 2)     * HID + j0 + c16) * HID + quad * 8;
    const ushort* wpB = whh + ((size_t)d * G4 + (size_t)(gp * 2 + 1) * HID + j0 + c16) * HID + quad * 8;
#pragma unroll
    for (int t = 0; t < 16; ++t){
      bfr0[t] = *(const bf16x8*)(wpA + (kh * 16 + t) * 32);
      bfr1[t] = *(const bf16x8*)(wpB + (kh * 16 + t) * 32);
    }
  }

  // ---- cell state: 2 units per thread, registers across the chunk ----
  float cv0 = cst[(size_t)lb * 512 + tid * 2];
  float cv1 = cst[(size_t)lb * 512 + tid * 2 + 1];

  const int tgt_t = mode ? tgt_idx[mb + er] : -1;

  // staging constants (per thread): linear LDS dest, src column pre-swizzled
  const int stColU = (tid * 8) & 1023;        // column (ushorts) this thread covers
  const int stRB   = tid >> 7;                // row parity bit
  const int myJtB  = (stColU >> 4) & ~3;      // aligned 4-producer group base

  // K-loop read swizzle (rows c16 / c16+16 share key (row&7))
  const int swz = (c16 & 7) << 3;
  const ushort* bA = hS + c16 * 1024;
  const ushort* bB = hS + (16 + c16) * 1024;

  // ---- stage step-0 panel + prefetch step-0 xw ----
  {
    const ushort* hp = hinit + (size_t)mb * D2H + d * HID;
#pragma unroll
    for (int r = 0; r < 16; ++r){
      int row  = 2 * r + stRB;
      int soff = stColU ^ ((row & 7) << 3);   // involution, matches read XOR
      async_ld16(hp + (size_t)row * D2H + soff, hS + tid * 8 + r * 2048);
    }
  }
  size_t xrow = ((size_t)d * CROWS + mb + er) * G4;
  uint32_t xq0 = *(const uint32_t*)(xw + xrow + 0 * HID + j0 + ec);
  uint32_t xq1 = *(const uint32_t*)(xw + xrow + 1 * HID + j0 + ec);
  uint32_t xq2 = *(const uint32_t*)(xw + xrow + 2 * HID + j0 + ec);
  uint32_t xq3 = *(const uint32_t*)(xw + xrow + 3 * HID + j0 + ec);

  for (int i = 0; i < CT; ++i){
    ushort* hout = hseq + (size_t)i * HSLOT;

    __builtin_amdgcn_s_waitcnt(0);         // (D) this thread's staging + xq landed
    __syncthreads();                       // all threads' staging done

    // ---- K-loop from LDS: half-K x 2 gates x 2 row-halves ----
    f32x4 a00 = {}, a01 = {}, a10 = {}, a11 = {};
#pragma unroll
    for (int t = 0; t < 16; ++t){
      int cidx = ((kh * 16 + t) * 32 + quad * 8) ^ swz;
      bf16x8 a0 = *(const bf16x8*)(bA + cidx);
      bf16x8 a1 = *(const bf16x8*)(bB + cidx);
      a00 = __builtin_amdgcn_mfma_f32_16x16x32_bf16(a0, bfr0[t], a00, 0, 0, 0);
      a01 = __builtin_amdgcn_mfma_f32_16x16x32_bf16(a1, bfr0[t], a01, 0, 0, 0);
      a10 = __builtin_amdgcn_mfma_f32_16x16x32_bf16(a0, bfr1[t], a10, 0, 0, 0);
      a11 = __builtin_amdgcn_mfma_f32_16x16x32_bf16(a1, bfr1[t], a11, 0, 0, 0);
    }

    // ---- two-phase partial-sum combine in sred ----
    const int G0 = gp * 2, G1 = gp * 2 + 1;
    if (kh == 1){
#pragma unroll
      for (int r = 0; r < 4; ++r){
        sred[(G0 * 32 +      quad * 4 + r) * 17 + c16] = a00[r];
        sred[(G0 * 32 + 16 + quad * 4 + r) * 17 + c16] = a01[r];
        sred[(G1 * 32 +      quad * 4 + r) * 17 + c16] = a10[r];
        sred[(G1 * 32 + 16 + quad * 4 + r) * 17 + c16] = a11[r];
      }
    }
    __syncthreads();                       // (A1) kh1 partials visible
    if (kh == 0){
#pragma unroll
      for (int r = 0; r < 4; ++r){
        sred[(G0 * 32 +      quad * 4 + r) * 17 + c16] += a00[r];
        sred[(G0 * 32 + 16 + quad * 4 + r) * 17 + c16] += a01[r];
        sred[(G1 * 32 +      quad * 4 + r) * 17 + c16] += a10[r];
        sred[(G1 * 32 + 16 + quad * 4 + r) * 17 + c16] += a11[r];
      }
    }
    __syncthreads();                       // (A2) sums complete

    // ---- per-thread LSTM pointwise for units (er,ec) and (er,ec+1) ----
    float i0 = sred[(0 * 32 + er) * 17 + ec]     + bf2f(xq0 & 0xffffu);
    float i1 = sred[(0 * 32 + er) * 17 + ec + 1] + bf2f(xq0 >> 16);
    float f0 = sred[(1 * 32 + er) * 17 + ec]     + bf2f(xq1 & 0xffffu);
    float f1 = sred[(1 * 32 + er) * 17 + ec + 1] + bf2f(xq1 >> 16);
    float g0 = sred[(2 * 32 + er) * 17 + ec]     + bf2f(xq2 & 0xffffu);
    float g1 = sred[(2 * 32 + er) * 17 + ec + 1] + bf2f(xq2 >> 16);
    float o0 = sred[(3 * 32 + er) * 17 + ec]     + bf2f(xq3 & 0xffffu);
    float o1 = sred[(3 * 32 + er) * 17 + ec + 1] + bf2f(xq3 >> 16);
    float c0 = sigm(f0) * cv0 + sigm(i0) * tanh_s(g0);
    float c1 = sigm(f1) * cv1 + sigm(i1) * tanh_s(g1);
    float h0 = sigm(o0) * tanh_s(c0);
    float h1 = sigm(o1) * tanh_s(c1);
    cv0 = c0; cv1 = c1;

    // write-through packed h (reaches coherence point; drained before flag store)
    uint32_t hp2 = (uint32_t)f2bf(h0) | ((uint32_t)f2bf(h1) << 16);
    size_t hoff = (size_t)(mb + er) * D2H + d * HID + j0 + ec;
    __hip_atomic_store((uint32_t*)(hout + hoff), hp2, __ATOMIC_RELAXED, __HIP_MEMORY_SCOPE_AGENT);

    if (mode && tgt_t == tbase + i){
      tgt_out[hoff]     = h0;
      tgt_out[hoff + 1] = h1;
    }

    // ---- flag + per-thread gated staging of next panel ----
    if (i != CT - 1){
      __atomic_signal_fence(__ATOMIC_SEQ_CST);
      __builtin_amdgcn_s_waitcnt(0);       // this wave's h stores drained
      __syncthreads();                     // (B) all waves drained; sred reads done
      if (tid == 0)
        __hip_atomic_store(fgrp + i * 64 + jt, tok, __ATOMIC_RELAXED, __HIP_MEMORY_SCOPE_AGENT);
      // prefetch next step's xw before polling (independent of h(t))
      xrow = ((size_t)d * CROWS + (size_t)(i + 1) * NBATCH + mb + er) * G4;
      xq0 = *(const uint32_t*)(xw + xrow + 0 * HID + j0 + ec);
      xq1 = *(const uint32_t*)(xw + xrow + 1 * HID + j0 + ec);
      xq2 = *(const uint32_t*)(xw + xrow + 2 * HID + j0 + ec);
      xq3 = *(const uint32_t*)(xw + xrow + 3 * HID + j0 + ec);
      // poll the aligned 4-producer group covering this thread's staged columns
      {
        const unsigned* fq = fgrp + i * 64 + myJtB;
        while (true){
          unsigned v0 = __hip_atomic_load(fq + 0, __ATOMIC_RELAXED, __HIP_MEMORY_SCOPE_AGENT);
          unsigned v1 = __hip_atomic_load(fq + 1, __ATOMIC_RELAXED, __HIP_MEMORY_SCOPE_AGENT);
          unsigned v2 = __hip_atomic_load(fq + 2, __ATOMIC_RELAXED, __HIP_MEMORY_SCOPE_AGENT);
          unsigned v3 = __hip_atomic_load(fq + 3, __ATOMIC_RELAXED, __HIP_MEMORY_SCOPE_AGENT);
          bool ok = (v0 >= tok) & (v1 >= tok) & (v2 >= tok) & (v3 >= tok);
          if (__all((int)ok)) break;
          __builtin_amdgcn_s_sleep(1);
        }
      }
      asm volatile("" ::: "memory");       // no hoisting of panel loads above poll
      // stage next panel rows for this thread's columns (producers done)
      {
        const ushort* hp3 = hseq + (size_t)i * HSLOT + (size_t)mb * D2H + d * HID;
#pragma unroll
        for (int r = 0; r < 16; ++r){
          int row  = 2 * r + stRB;
          int soff = stColU ^ ((row & 7) << 3);
          async_ld16(hp3 + (size_t)row * D2H + soff, hS + tid * 8 + r * 2048);
        }
      }
    }
  }

  cst[(size_t)lb * 512 + tid * 2]     = cv0;
  cst[(size_t)lb * 512 + tid * 2 + 1] = cv1;
}

// ---------------- final: out[b] = sigmoid(dot(tgt[b], w_cls) + b_cls) ----------------
__global__ __launch_bounds__(256) void k_final(const float* __restrict__ tgt,
                                               const float* __restrict__ wc,
                                               const float* __restrict__ bc,
                                               float* __restrict__ out){
  int b = blockIdx.x, tid = threadIdx.x;
  const float4* tv = (const float4*)(tgt + (size_t)b * D2H);
  const float4* wv = (const float4*)wc;
  float s = 0.f;
  for (int i = tid; i < D2H / 4; i += 256){
    float4 a = tv[i], ww = wv[i];
    s += a.x * ww.x + a.y * ww.y + a.z * ww.z + a.w * ww.w;
  }
  for (int off = 32; off; off >>= 1) s += __shfl_down(s, off, 64);
  __shared__ float red[4];
  if ((tid & 63) == 0) red[tid >> 6] = s;
  __syncthreads();
  if (tid == 0){
    float tot = red[0] + red[1] + red[2] + red[3] + bc[0];
    out[b] = 1.f / (1.f + __expf(-tot));
  }
}

extern "C" void kernel_launch(void* const* d_in, const int* in_sizes, int n_in,
                              void* d_out, int out_size, void* d_ws, size_t ws_size,
                              hipStream_t stream){
  (void)in_sizes; (void)n_in; (void)out_size;
  const int*   inp   = (const int*)  d_in[0];
  const int*   tgtix = (const int*)  d_in[1];
  const float* emb   = (const float*)d_in[2];
  const float* wih0  = (const float*)d_in[3];
  const float* whh0  = (const float*)d_in[4];
  const float* bl0   = (const float*)d_in[5];
  const float* wih1  = (const float*)d_in[6];
  const float* whh1  = (const float*)d_in[7];
  const float* bl1   = (const float*)d_in[8];
  const float* wcls  = (const float*)d_in[9];
  const float* bcls  = (const float*)d_in[10];
  float* out = (float*)d_out;

  // ---- workspace carve ----
  char* p = (char*)d_ws;
  ushort* wih0b = (ushort*)p; p += (size_t)2 * G4 * 1024 * 2;   // 16 MB
  ushort* whh0b = (ushort*)p; p += (size_t)2 * G4 * 1024 * 2;   // 16 MB
  ushort* wih1b = (ushort*)p; p += (size_t)2 * G4 * 2048 * 2;   // 32 MB
  ushort* whh1b = (ushort*)p; p += (size_t)2 * G4 * 1024 * 2;   // 16 MB
  ushort* xbf   = (ushort*)p; p += (size_t)CROWS * EMB * 2;     // 8 MB
  ushort* xw0   = (ushort*)p; p += (size_t)2 * CROWS * G4 * 2;  // 64 MB
  ushort* h0seq = (ushort*)p; p += (size_t)CT * HSLOT * 2;      // 16 MB rolling
  ushort* h1seq = (ushort*)p; p += (size_t)CT * HSLOT * 2;      // 16 MB rolling
  // ---- zeroed region ----
  char* zbase = p;
  ushort* h0zero = (ushort*)p; p += (size_t)HSLOT * 2;            // 256 KB
  float*  c0st   = (float*)p;  p += (size_t)256 * 512 * 4;        // 512 KB
  float*  c1st   = (float*)p;  p += (size_t)256 * 512 * 4;        // 512 KB
  unsigned* flags = (unsigned*)p; p += (size_t)2 * 4 * CT * 64 * 4; // 128 KB
  size_t zbytes = (size_t)(p - zbase);
  // ---- end zero region ----
  float* tgtb = (float*)p; p += (size_t)NBATCH * D2H * 4;       // 512 KB

  // second xw buffer (64 MB) enables the layer-pipelined schedule
  const size_t xwBytes = (size_t)2 * CROWS * G4 * 2;
  bool pipe = ((size_t)(p - (char*)d_ws) + xwBytes) <= ws_size;
  ushort* xw1 = pipe ? (ushort*)p : xw0;

  int zn = (int)(zbytes / 4);
  k_zero<<<dim3((zn + 255) / 256), 256, 0, stream>>>((uint32_t*)zbase, zn);
  k_convert<<<dim3(8192),  256, 0, stream>>>((const float4*)wih0, (ushort4*)wih0b, 2 * G4 * 1024 / 4);
  k_convert<<<dim3(8192),  256, 0, stream>>>((const float4*)whh0, (ushort4*)whh0b, 2 * G4 * 1024 / 4);
  k_convert<<<dim3(16384), 256, 0, stream>>>((const float4*)wih1, (ushort4*)wih1b, 2 * G4 * 2048 / 4);
  k_convert<<<dim3(8192),  256, 0, stream>>>((const float4*)whh1, (ushort4*)whh1b, 2 * G4 * 1024 / 4);

  const size_t cds = (size_t)CROWS * G4;

  if (pipe){
    // software-pipelined: dispatch t runs layer0 chunk t || layer1 chunk t-1
    for (int t = 0; t <= NC; ++t){
      if (t < NC){
        k_gather_c<<<dim3(CROWS), 256, 0, stream>>>(inp, emb, xbf, t * CT);
        k_gemm<<<dim3(CROWS / 128, G4 / 128, 2), 256, 0, stream>>>(xbf, wih0b, bl0, xw0, EMB, cds);
      }
      if (t >= 1)  // reads h0seq written by dispatch t-1's layer0 half
        k_gemm<<<dim3(CROWS / 128, G4 / 128, 2), 256, 0, stream>>>(h0seq, wih1b, bl1, xw1, D2H, cds);
      int act = (t < NC ? 1 : 0) | (t >= 1 ? 2 : 0);
      k_rec<<<dim3(512), 256, 0, stream>>>(xw0, xw1, whh0b, whh1b,
          (t == 0) ? h0zero : h0seq + (size_t)(CT - 1) * HSLOT,
          (t <= 1) ? h0zero : h1seq + (size_t)(CT - 1) * HSLOT,
          h0seq, h1seq, c0st, c1st, flags, act,
          t * CT, (t - 1) * CT,
          (unsigned)(t + 1), (unsigned)t,
          tgtix, tgtb);
    }
  } else {
    // fallback: serial schedule (xw1 == xw0)
    for (int c = 0; c < NC; ++c){
      int tbase = c * CT;
      k_gather_c<<<dim3(CROWS), 256, 0, stream>>>(inp, emb, xbf, tbase);
      k_gemm<<<dim3(CROWS / 128, G4 / 128, 2), 256, 0, stream>>>(xbf, wih0b, bl0, xw0, EMB, cds);
      k_rec<<<dim3(512), 256, 0, stream>>>(xw0, xw1, whh0b, whh1b,
          (c == 0) ? h0zero : h0seq + (size_t)(CT - 1) * HSLOT, h0zero,
          h0seq, h1seq, c0st, c1st, flags, 1,
          tbase, 0, (unsigned)(c + 1), 0u, tgtix, tgtb);
      k_gemm<<<dim3(CROWS / 128, G4 / 128, 2), 256, 0, stream>>>(h0seq, wih1b, bl1, xw1, D2H, cds);
      k_rec<<<dim3(512), 256, 0, stream>>>(xw0, xw1, whh0b, whh1b,
          h0zero, (c == 0) ? h0zero : h1seq + (size_t)(CT - 1) * HSLOT,
          h0seq, h1seq, c0st, c1st, flags, 2,
          0, tbase, 0u, (unsigned)(c + 1), tgtix, tgtb);
    }
  }

  k_final<<<dim3(NBATCH), 256, 0, stream>>>(tgtb, wcls, bcls, out);
}